// Round 12
// baseline (1055.944 us; speedup 1.0000x reference)
//
#include <hip/hip_runtime.h>
#include <math.h>

#define LL 64
#define BB 8
#define HH 512
#define H2 1024
#define VV 8192
#define NSENT 63
#define NPAIR 2016          // i<j pairs
#define NPITEM 2017         // + root (0,0)
#define MROWS 16136         // 2017*8
#define MPAD 16256          // 127*128
#define NEGV (-1e9f)
#define EPSV 4.5399929762484854e-05f

typedef unsigned int uint;
typedef unsigned short ushort;
using bf16x8 = __attribute__((ext_vector_type(8))) short;
using f32x4  = __attribute__((ext_vector_type(4))) float;

__device__ inline ushort f2bf(float x) {   // round-to-nearest-even
    uint u = __float_as_uint(x);
    uint r = (u + 0x7fffu + ((u >> 16) & 1u)) >> 16;
    return (ushort)r;
}
__device__ inline float bf2f(ushort x) {
    uint u = ((uint)x) << 16;
    return __uint_as_float(u);
}
// staged (MFMA-fragment-order) offset in ushorts for element (row, k), K=512
__device__ inline size_t staged_off(int row, int k) {
    return ((size_t)(row >> 4) << 13) + ((size_t)(k >> 5) << 9)
         + (((k >> 3) & 3) << 7) + ((row & 15) << 3) + (k & 7);
}
__device__ inline void gl_lds16(const ushort* g, ushort* l) {
    __builtin_amdgcn_global_load_lds(
        (const __attribute__((address_space(1))) unsigned int*)g,
        (__attribute__((address_space(3))) unsigned int*)l, 16, 0, 0);
}
// branchless online-LSE step; x = -inf is the identity
__device__ inline void lse_step(float& m, float& s, float x) {
    float M = fmaxf(m, x);
    s = s * __expf(m - M) + __expf(x - M);
    m = M;
}
__device__ inline void lse_comb(float& m, float& s, float mo, float so) {
    float M = fmaxf(m, mo);
    s = s * __expf(m - M) + so * __expf(mo - M);
    m = M;
}
// decode li -> (i, l) with li = i*(i+1)/2 + l, l <= i
__device__ inline void tri_decode(int li, int& i, int& l) {
    i = (int)((sqrtf(8.0f * (float)li + 1.0f) - 1.0f) * 0.5f);
    if ((i + 1) * (i + 2) / 2 <= li) i++;
    else if (i * (i + 1) / 2 > li) i--;
    l = li - i * (i + 1) / 2;
}

// ---------------------------------------------------------------- fused: W2w->bf16 staged (0..1023) + U/L GEMMs (1024..1279) + pair tables (1280..1287)
// NOTE: no table memset — every cell read by DP is either combine-written,
// earlier-gap DP-computed, or in the closed (i,i,*) i>0 garbage subgraph whose
// poisoned (finite) values never reach (0,0,63).
__global__ __launch_bounds__(256) void ulw2wt_kernel(
    const float* __restrict__ enc, const float* __restrict__ W1t,
    const float* __restrict__ W1w, const float* __restrict__ W2w,
    const int* __restrict__ sentence,
    float* __restrict__ UL, ushort* __restrict__ w2wT,
    int* __restrict__ pair_i, int* __restrict__ pair_j, int* __restrict__ words)
{
    __shared__ float smem[64 * 65];    // 16.6 KB, shared by both heavy paths
    if (blockIdx.x >= 1280) {
        // ---- pair tables
        const int p = (blockIdx.x - 1280) * 256 + threadIdx.x;
        if (p >= NPITEM) return;
        int i = 0, j = 0;
        if (p != NPAIR) {
            int base = 0;
            while (i < 62 && p >= base + (NSENT - i)) { base += NSENT - i; i++; }
            j = i + 1 + (p - base);
        }
        pair_i[p] = i; pair_j[p] = j;
        for (int b = 0; b < BB; b++) {
            int w;
            if (p == NPAIR)      w = sentence[1 * BB + b];
            else if (j <= 62)    w = sentence[(j + 1) * BB + b];
            else                 w = -1;
            words[p * BB + b] = w;
        }
        return;
    }
    if (blockIdx.x < 1024) {
        const int kt = blockIdx.x >> 7;      // 0..7
        const int nt = blockIdx.x & 127;     // 0..127
        const int k0 = kt * 64, n0 = nt * 64;
        for (int it = 0; it < 16; it++) {
            int idx = it * 256 + threadIdx.x;
            int kr = idx >> 6, nc = idx & 63;
            smem[kr * 65 + nc] = W2w[(size_t)(k0 + kr) * VV + n0 + nc];
        }
        __syncthreads();
        for (int it = 0; it < 8; it++) {
            int idx = it * 256 + threadIdx.x;
            int nr = idx >> 5, kc = (idx & 31) * 2;
            uint v = (uint)f2bf(smem[kc * 65 + nr]) | ((uint)f2bf(smem[(kc + 1) * 65 + nr]) << 16);
            *(uint*)&w2wT[staged_off(n0 + nr, k0 + kc)] = v;
        }
        return;
    }
    // ---- U/L factor GEMMs: UL[mat][l*8+b][u]
    const int bid = blockIdx.x - 1024;
    const int mat = bid >> 6;
    const int l = bid & 63;
    float* f = smem;    // [8][512]
    for (int t = threadIdx.x; t < BB * HH; t += 256)
        f[t] = enc[(size_t)l * BB * HH + t];
    __syncthreads();

    const float* W = (mat == 0) ? W1t : (mat == 1) ? (W1t + HH * HH)
                   : (mat == 2) ? W1w : (W1w + HH * HH);
    const int u0 = threadIdx.x;
    float acc0[BB], acc1[BB];
#pragma unroll
    for (int b = 0; b < BB; b++) { acc0[b] = 0.f; acc1[b] = 0.f; }
    for (int k = 0; k < HH; k += 4) {
        float4 fk[BB];
#pragma unroll
        for (int b = 0; b < BB; b++) fk[b] = *(const float4*)&f[b * HH + k];
#pragma unroll
        for (int kk = 0; kk < 4; kk++) {
            float w0 = W[(size_t)(k + kk) * HH + u0];
            float w1 = W[(size_t)(k + kk) * HH + u0 + 256];
#pragma unroll
            for (int b = 0; b < BB; b++) {
                float fb = ((const float*)&fk[b])[kk];
                acc0[b] = fmaf(fb, w0, acc0[b]);
                acc1[b] = fmaf(fb, w1, acc1[b]);
            }
        }
    }
    float* outp = UL + (size_t)mat * 512 * 512 + (size_t)(l * BB) * HH;
#pragma unroll
    for (int b = 0; b < BB; b++) {
        outp[b * HH + u0]       = acc0[b];
        outp[b * HH + u0 + 256] = acc1[b];
    }
}

// ---------------------------------------------------------------- per-pair: trans probs + hidden_w (bf16 staged) + gval (fused)
__global__ __launch_bounds__(256) void pairs_kernel(
    const float* __restrict__ UL, const float* __restrict__ b1t,
    const float* __restrict__ W2t, const float* __restrict__ b2t,
    const float* __restrict__ b1w, const int* __restrict__ pair_i,
    const int* __restrict__ pair_j, const int* __restrict__ words,
    const ushort* __restrict__ w2wT, const float* __restrict__ b2w,
    float* __restrict__ sh_log, float* __restrict__ red_log,
    float* __restrict__ red_logT, ushort* __restrict__ hbf,
    float* __restrict__ gval)
{
    const int p = blockIdx.x;
    const int i = pair_i[p], j = pair_j[p];
    const float* Ut = UL;
    const float* Lt = UL + 512 * 512;
    const float* Uw = UL + 2 * 512 * 512;
    const float* Lw = UL + 3 * 512 * 512;

    __shared__ float redm[4][BB];
    __shared__ float redg[4][BB];
    const int k0 = threadIdx.x * 2;
    const float2 b1wv = *(const float2*)&b1w[k0];
    const float2 b1tv = *(const float2*)&b1t[k0];
    const float2 w2tv = *(const float2*)&W2t[k0];
    const size_t kpart = ((size_t)(k0 >> 5) << 9) + (((k0 >> 3) & 3) << 7) + (k0 & 7);

    float part[BB], gv[BB];
#pragma unroll
    for (int b = 0; b < BB; b++) {
        const int row = p * BB + b;
        float2 u = *(const float2*)&Uw[(size_t)(i * BB + b) * HH + k0];
        float2 l = *(const float2*)&Lw[(size_t)(j * BB + b) * HH + k0];
        float h0 = u.x + l.x + b1wv.x; h0 = h0 > 0.f ? h0 : 0.f;
        float h1 = u.y + l.y + b1wv.y; h1 = h1 > 0.f ? h1 : 0.f;
        uint packed = (uint)f2bf(h0) | ((uint)f2bf(h1) << 16);
        *(uint*)&hbf[((size_t)(row >> 4) << 13) + kpart + ((row & 15) << 3)] = packed;
        // gval partial: h (f32) . w2wT[word] (bf16)
        const int word = words[row];
        if (word >= 0) {
            uint wv = *(const uint*)&w2wT[staged_off(word, k0)];
            gv[b] = h0 * bf2f((ushort)(wv & 0xffff)) + h1 * bf2f((ushort)(wv >> 16));
        } else gv[b] = 0.f;
        // trans hidden -> partial score
        float2 ut = *(const float2*)&Ut[(size_t)(i * BB + b) * HH + k0];
        float2 lt = *(const float2*)&Lt[(size_t)(j * BB + b) * HH + k0];
        float t0 = ut.x + lt.x + b1tv.x; t0 = t0 > 0.f ? t0 : 0.f;
        float t1 = ut.y + lt.y + b1tv.y; t1 = t1 > 0.f ? t1 : 0.f;
        part[b] = t0 * w2tv.x + t1 * w2tv.y;
    }

#pragma unroll
    for (int off = 32; off > 0; off >>= 1)
#pragma unroll
        for (int b = 0; b < BB; b++) {
            part[b] += __shfl_down(part[b], off, 64);
            gv[b]   += __shfl_down(gv[b], off, 64);
        }
    const int wave = threadIdx.x >> 6, lane = threadIdx.x & 63;
    if (lane == 0)
#pragma unroll
        for (int b = 0; b < BB; b++) { redm[wave][b] = part[b]; redg[wave][b] = gv[b]; }
    __syncthreads();
    if (threadIdx.x < BB) {
        const int b = threadIdx.x;
        const int word = words[p * BB + b];
        if (word >= 0) {
            float g = redg[0][b] + redg[1][b] + redg[2][b] + redg[3][b];
            gval[p * BB + b] = g + b2w[word];
        }
        if (p != NPAIR) {
            float sc = redm[0][b] + redm[1][b] + redm[2][b] + redm[3][b] + b2t[0];
            float pr = 1.f / (1.f + expf(-sc));
            const float rlv = logf(pr + EPSV);
            sh_log[(i * LL + j) * BB + b]   = log1pf(-pr + EPSV);
            red_log[(i * LL + j) * BB + b]  = rlv;
            red_logT[(j * LL + i) * BB + b] = rlv;
        }
    }
}

// ---------------------------------------------------------------- logits GEMM (MFMA, glds staging) + exp-sum partials
__global__ __launch_bounds__(256) void gemm_kernel(
    const ushort* __restrict__ hA, const ushort* __restrict__ w2wT,
    const float* __restrict__ b2w, float* __restrict__ part_s)
{
    const int mt = blockIdx.x >> 6;      // 0..126
    const int nt = blockIdx.x & 63;      // 0..63
    __shared__ ushort As[8192];          // 16 KB: 16 slabs of 512
    __shared__ ushort Bs[8192];

    const int tid = threadIdx.x;
    const int lane = tid & 63, w = tid >> 6;
    const int wm = w >> 1, wn = w & 1;
    const int quad = lane >> 4, l15 = lane & 15;

    f32x4 acc[4][4];
#pragma unroll
    for (int a = 0; a < 4; a++)
#pragma unroll
        for (int b = 0; b < 4; b++) acc[a][b] = (f32x4){0.f, 0.f, 0.f, 0.f};

    for (int kc = 0; kc < 8; kc++) {
        __syncthreads();
#pragma unroll
        for (int s = 0; s < 8; s++) {
            const int slab = w * 8 + s;
            const int sl = slab & 15;
            const int rt = sl >> 1, t = sl & 1;
            if (slab < 16) {
                const ushort* g = hA + ((size_t)(mt * 8 + rt) << 13)
                                + ((size_t)(2 * kc + t) << 9) + lane * 8;
                gl_lds16(g, &As[sl * 512]);
            } else {
                const ushort* g = w2wT + ((size_t)(nt * 8 + rt) << 13)
                                + ((size_t)(2 * kc + t) << 9) + lane * 8;
                gl_lds16(g, &Bs[sl * 512]);
            }
        }
        __syncthreads();
#pragma unroll
        for (int ks = 0; ks < 2; ks++) {
            bf16x8 af[4], bfr[4];
#pragma unroll
            for (int fm = 0; fm < 4; fm++)
                af[fm] = *(const bf16x8*)&As[((wm * 4 + fm) * 2 + ks) * 512 + lane * 8];
#pragma unroll
            for (int fn = 0; fn < 4; fn++)
                bfr[fn] = *(const bf16x8*)&Bs[((wn * 4 + fn) * 2 + ks) * 512 + lane * 8];
#pragma unroll
            for (int fm = 0; fm < 4; fm++)
#pragma unroll
                for (int fn = 0; fn < 4; fn++)
                    acc[fm][fn] = __builtin_amdgcn_mfma_f32_16x16x32_bf16(
                        af[fm], bfr[fn], acc[fm][fn], 0, 0, 0);
        }
    }

    float bias[4];
#pragma unroll
    for (int fn = 0; fn < 4; fn++)
        bias[fn] = b2w[nt * 128 + wn * 64 + fn * 16 + l15];
    const int pslot = nt * 2 + wn;
#pragma unroll
    for (int fm = 0; fm < 4; fm++) {
#pragma unroll
        for (int r = 0; r < 4; r++) {
            float s = __expf(acc[fm][0][r] + bias[0]) + __expf(acc[fm][1][r] + bias[1])
                    + __expf(acc[fm][2][r] + bias[2]) + __expf(acc[fm][3][r] + bias[3]);
            s += __shfl_xor(s, 1, 64);
            s += __shfl_xor(s, 2, 64);
            s += __shfl_xor(s, 4, 64);
            s += __shfl_xor(s, 8, 64);
            if (l15 == 0) {
                const int grow = mt * 128 + wm * 64 + fm * 16 + quad * 4 + r;
                part_s[(size_t)pslot * MPAD + grow] = s;
            }
        }
    }
}

// ---------------------------------------------------------------- combine exp-sum partials -> base cells (both tables)
__global__ __launch_bounds__(256) void combine_kernel(
    const float* __restrict__ part_s, const float* __restrict__ gval,
    const float* __restrict__ sh_log, const int* __restrict__ pair_i,
    const int* __restrict__ pair_j, float* __restrict__ table,
    float* __restrict__ tableB)
{
    const int row = blockIdx.x * 256 + threadIdx.x;
    if (row >= MROWS) return;
    const int p = row >> 3, b = row & 7;
    float S = 0.f;
    for (int nt = 0; nt < 128; nt++)
        S += part_s[(size_t)nt * MPAD + row];
    const float lse = logf(S);
    const float g = gval[row] - lse;
    const int i = pair_i[p], j = pair_j[p];
    if (p == NPAIR) {
        table[(size_t)((0 * LL + 0) * LL + 1) * BB + b]  = g;
        tableB[(size_t)((0 * LL + 1) * LL + 0) * BB + b] = g;
    } else if (j <= 62) {
        const float v = sh_log[(i * LL + j) * BB + b] + g;
        table[(size_t)((i * LL + j) * LL + (j + 1)) * BB + b]  = v;
        tableB[(size_t)((i * LL + (j + 1)) * LL + j) * BB + b] = v;
    }
}

// ---------------------------------------------------------------- DP: gap triple (G, G+1, G+2) per launch, triangular l<=i
template<int G>
__global__ __launch_bounds__(256) void dp_triple_t(
    const float* __restrict__ red_logT, float* __restrict__ table,
    float* __restrict__ tableB)
{
    constexpr int NE0 = (64 - G) * (65 - G) / 2;
    constexpr int NE1 = (63 - G) * (64 - G) / 2;
    constexpr int NE2 = (62 - G) * (63 - G) / 2;
    constexpr int E0 = NE0 * 32;
    constexpr int E1 = NE1 * 128;
    const int t = blockIdx.x * 256 + threadIdx.x;

    if (t < E0) {
        // ---------------- d0: gap G
        const int sub = t & 3;
        const int cell = t >> 2;
        const int b = cell & 7;
        int i, l; tri_decode(cell >> 3, i, l);
        const int j = i + G;
        const float* Tli  = table  + ((size_t)(l * LL + i) * LL) * BB + b;
        const float* TijB = tableB + ((size_t)(i * LL + j) * LL) * BB + b;
        const float* rlT  = red_logT + ((size_t)j * LL) * BB + b;
        float m = -3.4e38f, s = 0.f;
#pragma unroll
        for (int d = 0; d < (G + 2) / 4; d++) {
            const int k = i + 1 + sub + 4 * d;
            const float x = (k < j) ? (Tli[k * 8] + TijB[k * 8] + rlT[k * 8])
                                    : -INFINITY;
            lse_step(m, s, x);
        }
        lse_comb(m, s, __shfl_xor(m, 1, 64), __shfl_xor(s, 1, 64));
        lse_comb(m, s, __shfl_xor(m, 2, 64), __shfl_xor(s, 2, 64));
        if (sub == 0) {
            const float val = m + logf(s);
            table[(((size_t)l * LL + i) * LL + j) * BB + b]  = val;
            tableB[(((size_t)l * LL + j) * LL + i) * BB + b] = val;
        }
        return;
    }

    if (t < E0 + E1) {
        // ---------------- d1: gap G+1
        const int o = t - E0;
        const int r = o & 15;
        const int cell = o >> 4;
        const int b = cell & 7;
        int i, l; tri_decode(cell >> 3, i, l);
        const int j = i + G + 1;

        const float* Tli  = table  + ((size_t)(l * LL + i) * LL) * BB + b;
        const float* TijB = tableB + ((size_t)(i * LL + j) * LL) * BB + b;
        const float* rlT  = red_logT + ((size_t)j * LL) * BB + b;

        float m = -3.4e38f, s = 0.f;
        if (r < 4) {
            const float* Tij1B = tableB + ((size_t)(i * LL + (j - 1)) * LL) * BB + b;
            const float* rl1T  = red_logT + ((size_t)(j - 1) * LL) * BB + b;
#pragma unroll
            for (int d = 0; d < (G + 2) / 4; d++) {
                const int k = i + 1 + r + 4 * d;
                const float x = (k < j - 1) ? (Tli[k * 8] + Tij1B[k * 8] + rl1T[k * 8])
                                            : -INFINITY;
                lse_step(m, s, x);
            }
        } else if (r < 8) {
            const float* Ti1k = table  + ((size_t)(i * LL + (i + 1)) * LL) * BB + b;
            const float* TkjB = tableB + ((size_t)((i + 1) * LL + j) * LL) * BB + b;
#pragma unroll
            for (int d = 0; d < (G + 2) / 4; d++) {
                const int k = i + 2 + (r - 4) + 4 * d;
                const float x = (k < j) ? (Ti1k[k * 8] + TkjB[k * 8] + rlT[k * 8])
                                        : -INFINITY;
                lse_step(m, s, x);
            }
        } else {
#pragma unroll
            for (int d = 0; d < (G + 5) / 8; d++) {
                const int k = i + 2 + (r - 8) + 8 * d;
                const float x = (k < j - 1) ? (Tli[k * 8] + TijB[k * 8] + rlT[k * 8])
                                            : -INFINITY;
                lse_step(m, s, x);
            }
        }
        lse_comb(m, s, __shfl_xor(m, 1, 64), __shfl_xor(s, 1, 64));
        lse_comb(m, s, __shfl_xor(m, 2, 64), __shfl_xor(s, 2, 64));
        if (r >= 8)
            lse_comb(m, s, __shfl_xor(m, 4, 64), __shfl_xor(s, 4, 64));
        const int base = (threadIdx.x & 63) & ~15;
        float m1 = __shfl(m, base + 0, 64), s1 = __shfl(s, base + 0, 64);
        float m2 = __shfl(m, base + 4, 64), s2 = __shfl(s, base + 4, 64);
        float M  = __shfl(m, base + 8, 64), S  = __shfl(s, base + 8, 64);
        const float r1 = m1 + logf(s1);
        const float r2 = m2 + logf(s2);
        lse_step(M, S, Tli[(i + 1) * 8] + r2 + rlT[(i + 1) * 8]);
        lse_step(M, S, r1 + TijB[(j - 1) * 8] + rlT[(j - 1) * 8]);
        const float val = M + logf(S);
        if (r == 0) {
            table[(((size_t)l * LL + i) * LL + j) * BB + b]  = val;
            tableB[(((size_t)l * LL + j) * LL + i) * BB + b] = val;
        }
        return;
    }

    // ---------------- d2: gap G+2
    const int o2 = t - E0 - E1;
    if (o2 >= NE2 * 256) return;
    const int r = o2 & 31;
    const int cell = o2 >> 5;
    const int b = cell & 7;
    int i, l; tri_decode(cell >> 3, i, l);
    const int j = i + G + 2;

    const float* Tli  = table  + ((size_t)(l * LL + i) * LL) * BB + b;
    const float* Ti1  = table  + ((size_t)(i * LL + (i + 1)) * LL) * BB + b;
    const float* Ti2  = table  + ((size_t)(i * LL + (i + 2)) * LL) * BB + b;
    const float* Ti12 = table  + ((size_t)((i + 1) * LL + (i + 2)) * LL) * BB + b;
    const float* TBiG  = tableB + ((size_t)(i * LL + (i + G)) * LL) * BB + b;
    const float* TB1G1 = tableB + ((size_t)((i + 1) * LL + (i + G + 1)) * LL) * BB + b;
    const float* TB2j  = tableB + ((size_t)((i + 2) * LL + j) * LL) * BB + b;
    const float* TBiG1 = tableB + ((size_t)(i * LL + (i + G + 1)) * LL) * BB + b;
    const float* TB1j  = tableB + ((size_t)((i + 1) * LL + j) * LL) * BB + b;
    const float* TBij  = tableB + ((size_t)(i * LL + j) * LL) * BB + b;
    const float* Rj  = red_logT + ((size_t)j * LL) * BB + b;
    const float* RG  = red_logT + ((size_t)(i + G) * LL) * BB + b;
    const float* RG1 = red_logT + ((size_t)(i + G + 1) * LL) * BB + b;

    const int loop = r >> 2, s4 = r & 3;
    const float *A, *Bp, *R;
    int ks, ke;
    switch (loop) {
        case 0: A = Tli;  Bp = TBiG;  R = RG;  ks = i + 1; ke = i + G;     break; // P1
        case 1: A = Ti1;  Bp = TB1G1; R = RG1; ks = i + 2; ke = i + G + 1; break; // P3
        case 2: A = Ti2;  Bp = TB2j;  R = Rj;  ks = i + 3; ke = i + G + 2; break; // P4
        case 3: A = Ti12; Bp = TB2j;  R = Rj;  ks = i + 3; ke = i + G + 2; break; // P6
        case 4: A = Tli;  Bp = TBiG1; R = RG1; ks = i + 2; ke = i + G;     break; // P2mid
        case 5: A = Ti1;  Bp = TB1j;  R = Rj;  ks = i + 3; ke = i + G + 1; break; // P5mid
        case 6: A = Tli;  Bp = TBij;  R = Rj;  ks = i + 3; ke = i + G;     break; // mainmid
        default: A = Tli; Bp = TBij;  R = Rj;  ks = 0;     ke = 0;         break; // idle
    }
    float m = -3.4e38f, s = 0.f;
#pragma unroll
    for (int d = 0; d < (G + 2) / 4; d++) {
        const int k = ks + s4 + 4 * d;
        const float x = (k < ke) ? (A[k * 8] + Bp[k * 8] + R[k * 8]) : -INFINITY;
        lse_step(m, s, x);
    }
    lse_comb(m, s, __shfl_xor(m, 1, 64), __shfl_xor(s, 1, 64));
    lse_comb(m, s, __shfl_xor(m, 2, 64), __shfl_xor(s, 2, 64));
    const int wb = (threadIdx.x & 63) & ~31;
    float mv[7], sv[7];
#pragma unroll
    for (int q = 0; q < 7; q++) {
        mv[q] = __shfl(m, wb + 4 * q, 64);
        sv[q] = __shfl(s, wb + 4 * q, 64);
    }
    const float P1v = mv[0] + logf(sv[0]);
    const float P3v = mv[1] + logf(sv[1]);
    const float P4v = mv[2] + logf(sv[2]);
    const float P6v = mv[3] + logf(sv[3]);
    float m2 = mv[4], s2 = sv[4];
    lse_step(m2, s2, Tli[(i + 1) * 8] + P3v + RG1[(i + 1) * 8]);
    lse_step(m2, s2, P1v + table[(((size_t)i * LL + (i + G)) * LL + (i + G + 1)) * BB + b]
                     + RG1[(i + G) * 8]);
    const float P2v = m2 + logf(s2);
    float m5 = mv[5], s5 = sv[5];
    lse_step(m5, s5, Ti1[(i + 2) * 8] + P6v + Rj[(i + 2) * 8]);
    lse_step(m5, s5, P3v + table[(((size_t)(i + 1) * LL + (i + G + 1)) * LL + j) * BB + b]
                     + Rj[(i + G + 1) * 8]);
    const float P5v = m5 + logf(s5);
    float M = mv[6], S = sv[6];
    lse_step(M, S, Tli[(i + 1) * 8] + P5v + Rj[(i + 1) * 8]);
    lse_step(M, S, P2v + table[(((size_t)i * LL + (i + G + 1)) * LL + j) * BB + b]
                   + Rj[(i + G + 1) * 8]);
    if (G > 2) {
        lse_step(M, S, Tli[(i + 2) * 8] + P4v + Rj[(i + 2) * 8]);
        lse_step(M, S, P1v + table[(((size_t)i * LL + (i + G)) * LL + j) * BB + b]
                       + Rj[(i + G) * 8]);
    } else {
        lse_step(M, S, P1v + P4v + Rj[(i + 2) * 8]);   // k=i+2 == i+G
    }
    const float val = M + logf(S);
    if (r == 0) {
        table[(((size_t)l * LL + i) * LL + j) * BB + b]  = val;
        tableB[(((size_t)l * LL + j) * LL + i) * BB + b] = val;
    }
}

static void launch_dp(int G, const float* red_logT, float* table, float* tableB,
                      hipStream_t stream) {
    const int NE0 = (64 - G) * (65 - G) / 2;
    const int NE1 = (63 - G) * (64 - G) / 2;
    const int NE2 = (62 - G) * (63 - G) / 2;
    const int total = NE0 * 32 + NE1 * 128 + NE2 * 256;
    const int blocks = (total + 255) / 256;
#define DPC(GG) case GG: dp_triple_t<GG><<<blocks, 256, 0, stream>>>(red_logT, table, tableB); break;
    switch (G) {
        DPC(2)  DPC(5)  DPC(8)  DPC(11) DPC(14) DPC(17)
        DPC(20) DPC(23) DPC(26) DPC(29) DPC(32) DPC(35)
    }
#undef DPC
}

// ---------------------------------------------------------------- DP tail: gaps 38..63 in ONE block, barrier between levels
// Intra-block global write -> __syncthreads -> read is CU-local coherent
// (validated R5). Fixed 16-deep predicated unroll with clamped addresses so
// all loads issue before the dependent LSE chain (avoids R5's latency serialization).
__global__ __launch_bounds__(1024) void dp_tail_kernel(
    const float* __restrict__ red_logT, float* __restrict__ table,
    float* __restrict__ tableB, float* __restrict__ out)
{
    for (int g = 38; g <= 63; g++) {
        const int NC = (64 - g) * (65 - g) / 2;
        const int total = NC * 32;
        for (int t = threadIdx.x; t < total; t += 1024) {
            const int sub = t & 3;
            const int cell = t >> 2;
            const int b = cell & 7;
            int i, l; tri_decode(cell >> 3, i, l);
            const int j = i + g;
            const float* Tli  = table  + ((size_t)(l * LL + i) * LL) * BB + b;
            const float* TijB = tableB + ((size_t)(i * LL + j) * LL) * BB + b;
            const float* rlT  = red_logT + ((size_t)j * LL) * BB + b;
            float m = -3.4e38f, s = 0.f;
#pragma unroll
            for (int d = 0; d < 16; d++) {
                const int k = i + 1 + sub + 4 * d;
                const int kc = k < j ? k : j - 1;      // clamped: load always valid
                float x = Tli[kc * 8] + TijB[kc * 8] + rlT[kc * 8];
                x = (k < j) ? x : -INFINITY;
                lse_step(m, s, x);
            }
            lse_comb(m, s, __shfl_xor(m, 1, 64), __shfl_xor(s, 1, 64));
            lse_comb(m, s, __shfl_xor(m, 2, 64), __shfl_xor(s, 2, 64));
            if (sub == 0) {
                const float val = m + logf(s);
                table[(((size_t)l * LL + i) * LL + j) * BB + b]  = val;
                tableB[(((size_t)l * LL + j) * LL + i) * BB + b] = val;
                if (g == 63) out[b] = val;   // only cell (0,0,63) at g=63
            }
        }
        __syncthreads();
    }
}

// ---------------------------------------------------------------- launch
extern "C" void kernel_launch(void* const* d_in, const int* in_sizes, int n_in,
                              void* d_out, int out_size, void* d_ws, size_t ws_size,
                              hipStream_t stream) {
    const float* enc      = (const float*)d_in[0];
    const int*   sentence = (const int*)  d_in[1];
    const float* W1t      = (const float*)d_in[2];
    const float* b1t      = (const float*)d_in[3];
    const float* W2t      = (const float*)d_in[4];
    const float* b2t      = (const float*)d_in[5];
    const float* W1w      = (const float*)d_in[6];
    const float* b1w      = (const float*)d_in[7];
    const float* W2w      = (const float*)d_in[8];
    const float* b2w      = (const float*)d_in[9];
    float* out = (float*)d_out;

    float* base = (float*)d_ws;
    float* table    = base;                base += (size_t)LL * LL * LL * BB;   // 8 MB
    float* tableB   = base;                base += (size_t)LL * LL * LL * BB;   // 8 MB
    float* sh_log   = base;                base += LL * LL * BB;
    float* red_log  = base;                base += LL * LL * BB;
    float* red_logT = base;                base += LL * LL * BB;
    float* UL       = base;                base += 4 * 512 * 512;
    float* part_s   = base;                base += (size_t)128 * MPAD;
    float* gval     = base;                base += MPAD;
    int*   words    = (int*)base;          base += MPAD;
    int*   pair_i   = (int*)base;          base += 2048;
    int*   pair_j   = (int*)base;          base += 2048;
    ushort* hbf     = (ushort*)base;       base += (size_t)MPAD * HH / 2;
    ushort* w2wT    = (ushort*)base;       base += (size_t)VV * HH / 2;

    ulw2wt_kernel<<<1288, 256, 0, stream>>>(enc, W1t, W1w, W2w, sentence,
                                            UL, w2wT, pair_i, pair_j, words);
    pairs_kernel<<<NPITEM, 256, 0, stream>>>(UL, b1t, W2t, b2t, b1w,
                                             pair_i, pair_j, words, w2wT, b2w,
                                             sh_log, red_log, red_logT, hbf, gval);
    gemm_kernel<<<127 * 64, 256, 0, stream>>>(hbf, w2wT, b2w, part_s);
    combine_kernel<<<64, 256, 0, stream>>>(part_s, gval, sh_log, pair_i, pair_j,
                                           table, tableB);
    for (int G = 2; G <= 35; G += 3)
        launch_dp(G, red_logT, table, tableB, stream);
    dp_tail_kernel<<<1, 1024, 0, stream>>>(red_logT, table, tableB, out);
}

// Round 13
// 498.702 us; speedup vs baseline: 2.1174x; 2.1174x over previous
//
#include <hip/hip_runtime.h>
#include <math.h>

#define LL 64
#define BB 8
#define HH 512
#define H2 1024
#define VV 8192
#define NSENT 63
#define NPAIR 2016          // i<j pairs
#define NPITEM 2017         // + root (0,0)
#define MROWS 16136         // 2017*8
#define MPAD 16256          // 127*128
#define NEGV (-1e9f)
#define EPSV 4.5399929762484854e-05f

typedef unsigned int uint;
typedef unsigned short ushort;
typedef unsigned char uchar;
using f32x4  = __attribute__((ext_vector_type(4))) float;

// staged (MFMA-fragment-order) BYTE offset for fp8 element (row, k), K=512:
// row-tile of 16 x k-slab of 32 = 512 B; lane map: l15=row&15, quad=(k>>3)&3
__device__ inline size_t staged8(int row, int k) {
    return ((size_t)(row >> 4) << 13) + ((size_t)(k >> 5) << 9)
         + (((k >> 3) & 3) << 7) + ((row & 15) << 3) + (k & 7);
}
__device__ inline void gl_lds16(const void* g, void* l) {
    __builtin_amdgcn_global_load_lds(
        (const __attribute__((address_space(1))) unsigned int*)g,
        (__attribute__((address_space(3))) unsigned int*)l, 16, 0, 0);
}
// branchless online-LSE step; x = -inf is the identity
__device__ inline void lse_step(float& m, float& s, float x) {
    float M = fmaxf(m, x);
    s = s * __expf(m - M) + __expf(x - M);
    m = M;
}
__device__ inline void lse_comb(float& m, float& s, float mo, float so) {
    float M = fmaxf(m, mo);
    s = s * __expf(m - M) + so * __expf(mo - M);
    m = M;
}
// decode li -> (i, l) with li = i*(i+1)/2 + l, l <= i
__device__ inline void tri_decode(int li, int& i, int& l) {
    i = (int)((sqrtf(8.0f * (float)li + 1.0f) - 1.0f) * 0.5f);
    if ((i + 1) * (i + 2) / 2 <= li) i++;
    else if (i * (i + 1) / 2 > li) i--;
    l = li - i * (i + 1) / 2;
}

// ---------------------------------------------------------------- fused: W2w->fp8 staged (0..1023) + U/L GEMMs (1024..1279) + pair tables (1280..1287)
// No table memset: every DP-read cell is combine-written, earlier-gap computed,
// or in the closed (i,i,*) i>0 garbage subgraph (finite poison, never reaches root).
__global__ __launch_bounds__(256) void ulw2wt_kernel(
    const float* __restrict__ enc, const float* __restrict__ W1t,
    const float* __restrict__ W1w, const float* __restrict__ W2w,
    const int* __restrict__ sentence,
    float* __restrict__ UL, uchar* __restrict__ w2w8,
    int* __restrict__ pair_i, int* __restrict__ pair_j, int* __restrict__ words)
{
    __shared__ float smem[64 * 65];    // 16.6 KB
    if (blockIdx.x >= 1280) {
        const int p = (blockIdx.x - 1280) * 256 + threadIdx.x;
        if (p >= NPITEM) return;
        int i = 0, j = 0;
        if (p != NPAIR) {
            int base = 0;
            while (i < 62 && p >= base + (NSENT - i)) { base += NSENT - i; i++; }
            j = i + 1 + (p - base);
        }
        pair_i[p] = i; pair_j[p] = j;
        for (int b = 0; b < BB; b++) {
            int w;
            if (p == NPAIR)      w = sentence[1 * BB + b];
            else if (j <= 62)    w = sentence[(j + 1) * BB + b];
            else                 w = -1;
            words[p * BB + b] = w;
        }
        return;
    }
    if (blockIdx.x < 1024) {
        const int kt = blockIdx.x >> 7;      // 0..7
        const int nt = blockIdx.x & 127;     // 0..127
        const int k0 = kt * 64, n0 = nt * 64;
        for (int it = 0; it < 16; it++) {
            int idx = it * 256 + threadIdx.x;
            int kr = idx >> 6, nc = idx & 63;
            smem[kr * 65 + nc] = W2w[(size_t)(k0 + kr) * VV + n0 + nc];
        }
        __syncthreads();
        // W2w scaled x16 into fp8 e4m3 (epilogue divides by 16)
        for (int it = 0; it < 8; it++) {
            int idx = it * 256 + threadIdx.x;
            int nr = idx >> 5, kc = (idx & 31) * 2;
            int pk = __builtin_amdgcn_cvt_pk_fp8_f32(
                16.f * smem[kc * 65 + nr], 16.f * smem[(kc + 1) * 65 + nr], 0, false);
            *(ushort*)&w2w8[staged8(n0 + nr, k0 + kc)] = (ushort)pk;
        }
        return;
    }
    // ---- U/L factor GEMMs: UL[mat][l*8+b][u]
    const int bid = blockIdx.x - 1024;
    const int mat = bid >> 6;
    const int l = bid & 63;
    float* f = smem;    // [8][512]
    for (int t = threadIdx.x; t < BB * HH; t += 256)
        f[t] = enc[(size_t)l * BB * HH + t];
    __syncthreads();

    const float* W = (mat == 0) ? W1t : (mat == 1) ? (W1t + HH * HH)
                   : (mat == 2) ? W1w : (W1w + HH * HH);
    const int u0 = threadIdx.x;
    float acc0[BB], acc1[BB];
#pragma unroll
    for (int b = 0; b < BB; b++) { acc0[b] = 0.f; acc1[b] = 0.f; }
    for (int k = 0; k < HH; k += 4) {
        float4 fk[BB];
#pragma unroll
        for (int b = 0; b < BB; b++) fk[b] = *(const float4*)&f[b * HH + k];
#pragma unroll
        for (int kk = 0; kk < 4; kk++) {
            float w0 = W[(size_t)(k + kk) * HH + u0];
            float w1 = W[(size_t)(k + kk) * HH + u0 + 256];
#pragma unroll
            for (int b = 0; b < BB; b++) {
                float fb = ((const float*)&fk[b])[kk];
                acc0[b] = fmaf(fb, w0, acc0[b]);
                acc1[b] = fmaf(fb, w1, acc1[b]);
            }
        }
    }
    float* outp = UL + (size_t)mat * 512 * 512 + (size_t)(l * BB) * HH;
#pragma unroll
    for (int b = 0; b < BB; b++) {
        outp[b * HH + u0]       = acc0[b];
        outp[b * HH + u0 + 256] = acc1[b];
    }
}

// ---------------------------------------------------------------- per-pair: trans probs + hidden_w (fp8 staged) + gval (fused)
__global__ __launch_bounds__(256) void pairs_kernel(
    const float* __restrict__ UL, const float* __restrict__ b1t,
    const float* __restrict__ W2t, const float* __restrict__ b2t,
    const float* __restrict__ b1w, const int* __restrict__ pair_i,
    const int* __restrict__ pair_j, const int* __restrict__ words,
    const uchar* __restrict__ w2w8, const float* __restrict__ b2w,
    float* __restrict__ sh_log, float* __restrict__ red_log,
    float* __restrict__ red_logT, uchar* __restrict__ h8,
    float* __restrict__ gval)
{
    const int p = blockIdx.x;
    const int i = pair_i[p], j = pair_j[p];
    const float* Ut = UL;
    const float* Lt = UL + 512 * 512;
    const float* Uw = UL + 2 * 512 * 512;
    const float* Lw = UL + 3 * 512 * 512;

    __shared__ float redm[4][BB];
    __shared__ float redg[4][BB];
    const int k0 = threadIdx.x * 2;
    const float2 b1wv = *(const float2*)&b1w[k0];
    const float2 b1tv = *(const float2*)&b1t[k0];
    const float2 w2tv = *(const float2*)&W2t[k0];
    const size_t kpart = ((size_t)(k0 >> 5) << 9) + (((k0 >> 3) & 3) << 7) + (k0 & 7);

    float part[BB], gv[BB];
#pragma unroll
    for (int b = 0; b < BB; b++) {
        const int row = p * BB + b;
        float2 u = *(const float2*)&Uw[(size_t)(i * BB + b) * HH + k0];
        float2 l = *(const float2*)&Lw[(size_t)(j * BB + b) * HH + k0];
        float h0 = u.x + l.x + b1wv.x; h0 = h0 > 0.f ? h0 : 0.f;
        float h1 = u.y + l.y + b1wv.y; h1 = h1 > 0.f ? h1 : 0.f;
        int pk = __builtin_amdgcn_cvt_pk_fp8_f32(h0, h1, 0, false);
        *(ushort*)&h8[((size_t)(row >> 4) << 13) + kpart + ((row & 15) << 3)] = (ushort)pk;
        // gval partial: h (f32) . w2w8[word] (fp8, x16) / 16
        const int word = words[row];
        if (word >= 0) {
            int wv = *(const ushort*)&w2w8[staged8(word, k0)];
            float w0 = __builtin_amdgcn_cvt_f32_fp8(wv, 0);
            float w1 = __builtin_amdgcn_cvt_f32_fp8(wv, 1);
            gv[b] = (h0 * w0 + h1 * w1) * 0.0625f;
        } else gv[b] = 0.f;
        // trans hidden -> partial score
        float2 ut = *(const float2*)&Ut[(size_t)(i * BB + b) * HH + k0];
        float2 lt = *(const float2*)&Lt[(size_t)(j * BB + b) * HH + k0];
        float t0 = ut.x + lt.x + b1tv.x; t0 = t0 > 0.f ? t0 : 0.f;
        float t1 = ut.y + lt.y + b1tv.y; t1 = t1 > 0.f ? t1 : 0.f;
        part[b] = t0 * w2tv.x + t1 * w2tv.y;
    }

#pragma unroll
    for (int off = 32; off > 0; off >>= 1)
#pragma unroll
        for (int b = 0; b < BB; b++) {
            part[b] += __shfl_down(part[b], off, 64);
            gv[b]   += __shfl_down(gv[b], off, 64);
        }
    const int wave = threadIdx.x >> 6, lane = threadIdx.x & 63;
    if (lane == 0)
#pragma unroll
        for (int b = 0; b < BB; b++) { redm[wave][b] = part[b]; redg[wave][b] = gv[b]; }
    __syncthreads();
    if (threadIdx.x < BB) {
        const int b = threadIdx.x;
        const int word = words[p * BB + b];
        if (word >= 0) {
            float g = redg[0][b] + redg[1][b] + redg[2][b] + redg[3][b];
            gval[p * BB + b] = g + b2w[word];
        }
        if (p != NPAIR) {
            float sc = redm[0][b] + redm[1][b] + redm[2][b] + redm[3][b] + b2t[0];
            float pr = 1.f / (1.f + expf(-sc));
            const float rlv = logf(pr + EPSV);
            sh_log[(i * LL + j) * BB + b]   = log1pf(-pr + EPSV);
            red_log[(i * LL + j) * BB + b]  = rlv;
            red_logT[(j * LL + i) * BB + b] = rlv;
        }
    }
}

// ---------------------------------------------------------------- logits GEMM (fp8 MFMA, glds staging) + exp-sum partials
__global__ __launch_bounds__(256) void gemm_kernel(
    const uchar* __restrict__ h8, const uchar* __restrict__ w2w8,
    const float* __restrict__ b2w, float* __restrict__ part_s)
{
    const int mt = blockIdx.x >> 6;      // 0..126
    const int nt = blockIdx.x & 63;      // 0..63
    __shared__ uchar As[8192];           // 8 KB: 8 row-tiles x 1024 B (2 k-slabs)
    __shared__ uchar Bs[8192];

    const int tid = threadIdx.x;
    const int lane = tid & 63, w = tid >> 6;
    const int wm = w >> 1, wn = w & 1;
    const int quad = lane >> 4, l15 = lane & 15;

    f32x4 acc[4][4];
#pragma unroll
    for (int a = 0; a < 4; a++)
#pragma unroll
        for (int b = 0; b < 4; b++) acc[a][b] = (f32x4){0.f, 0.f, 0.f, 0.f};

    for (int kc = 0; kc < 8; kc++) {
        __syncthreads();
        // 16 glds (8 A row-tiles + 8 B row-tiles), 4 per wave, 1024 B each
#pragma unroll
        for (int s = 0; s < 4; s++) {
            const int slab = w * 4 + s;          // 0..15
            const int rt = slab & 7;
            if (slab < 8) {
                const uchar* g = h8 + ((size_t)(mt * 8 + rt) << 13)
                               + ((size_t)kc << 10) + lane * 16;
                gl_lds16(g, &As[rt * 1024]);
            } else {
                const uchar* g = w2w8 + ((size_t)(nt * 8 + rt) << 13)
                               + ((size_t)kc << 10) + lane * 16;
                gl_lds16(g, &Bs[rt * 1024]);
            }
        }
        __syncthreads();
#pragma unroll
        for (int ks = 0; ks < 2; ks++) {
            long af[4], bfr[4];
#pragma unroll
            for (int fm = 0; fm < 4; fm++)
                af[fm] = *(const long*)&As[(wm * 4 + fm) * 1024 + ks * 512 + quad * 128 + l15 * 8];
#pragma unroll
            for (int fn = 0; fn < 4; fn++)
                bfr[fn] = *(const long*)&Bs[(wn * 4 + fn) * 1024 + ks * 512 + quad * 128 + l15 * 8];
#pragma unroll
            for (int fm = 0; fm < 4; fm++)
#pragma unroll
                for (int fn = 0; fn < 4; fn++)
                    acc[fm][fn] = __builtin_amdgcn_mfma_f32_16x16x32_fp8_fp8(
                        af[fm], bfr[fn], acc[fm][fn], 0, 0, 0);
        }
    }

    float bias[4];
#pragma unroll
    for (int fn = 0; fn < 4; fn++)
        bias[fn] = b2w[nt * 128 + wn * 64 + fn * 16 + l15];
    const int pslot = nt * 2 + wn;
#pragma unroll
    for (int fm = 0; fm < 4; fm++) {
#pragma unroll
        for (int r = 0; r < 4; r++) {
            // W was scaled x16 into fp8 -> logits = acc/16 + bias
            float s = __expf(acc[fm][0][r] * 0.0625f + bias[0])
                    + __expf(acc[fm][1][r] * 0.0625f + bias[1])
                    + __expf(acc[fm][2][r] * 0.0625f + bias[2])
                    + __expf(acc[fm][3][r] * 0.0625f + bias[3]);
            s += __shfl_xor(s, 1, 64);
            s += __shfl_xor(s, 2, 64);
            s += __shfl_xor(s, 4, 64);
            s += __shfl_xor(s, 8, 64);
            if (l15 == 0) {
                const int grow = mt * 128 + wm * 64 + fm * 16 + quad * 4 + r;
                part_s[(size_t)pslot * MPAD + grow] = s;
            }
        }
    }
}

// ---------------------------------------------------------------- combine exp-sum partials -> base cells (both tables)
__global__ __launch_bounds__(256) void combine_kernel(
    const float* __restrict__ part_s, const float* __restrict__ gval,
    const float* __restrict__ sh_log, const int* __restrict__ pair_i,
    const int* __restrict__ pair_j, float* __restrict__ table,
    float* __restrict__ tableB)
{
    const int row = blockIdx.x * 256 + threadIdx.x;
    if (row >= MROWS) return;
    const int p = row >> 3, b = row & 7;
    float S = 0.f;
    for (int nt = 0; nt < 128; nt++)
        S += part_s[(size_t)nt * MPAD + row];
    const float lse = logf(S);
    const float g = gval[row] - lse;
    const int i = pair_i[p], j = pair_j[p];
    if (p == NPAIR) {
        table[(size_t)((0 * LL + 0) * LL + 1) * BB + b]  = g;
        tableB[(size_t)((0 * LL + 1) * LL + 0) * BB + b] = g;
    } else if (j <= 62) {
        const float v = sh_log[(i * LL + j) * BB + b] + g;
        table[(size_t)((i * LL + j) * LL + (j + 1)) * BB + b]  = v;
        tableB[(size_t)((i * LL + (j + 1)) * LL + j) * BB + b] = v;
    }
}

// ---------------------------------------------------------------- DP: gap triple (G, G+1, G+2) per launch, triangular l<=i
template<int G>
__global__ __launch_bounds__(256) void dp_triple_t(
    const float* __restrict__ red_logT, float* __restrict__ table,
    float* __restrict__ tableB, float* __restrict__ out)
{
    constexpr int NE0 = (64 - G) * (65 - G) / 2;
    constexpr int NE1 = (63 - G) * (64 - G) / 2;
    constexpr int NE2 = (62 - G) * (63 - G) / 2;
    constexpr int E0 = NE0 * 32;
    constexpr int E1 = NE1 * 128;
    const int t = blockIdx.x * 256 + threadIdx.x;

    if (t < E0) {
        // ---------------- d0: gap G
        const int sub = t & 3;
        const int cell = t >> 2;
        const int b = cell & 7;
        int i, l; tri_decode(cell >> 3, i, l);
        const int j = i + G;
        const float* Tli  = table  + ((size_t)(l * LL + i) * LL) * BB + b;
        const float* TijB = tableB + ((size_t)(i * LL + j) * LL) * BB + b;
        const float* rlT  = red_logT + ((size_t)j * LL) * BB + b;
        float m = -3.4e38f, s = 0.f;
#pragma unroll
        for (int d = 0; d < (G + 2) / 4; d++) {
            const int k = i + 1 + sub + 4 * d;
            const float x = (k < j) ? (Tli[k * 8] + TijB[k * 8] + rlT[k * 8])
                                    : -INFINITY;
            lse_step(m, s, x);
        }
        lse_comb(m, s, __shfl_xor(m, 1, 64), __shfl_xor(s, 1, 64));
        lse_comb(m, s, __shfl_xor(m, 2, 64), __shfl_xor(s, 2, 64));
        if (sub == 0) {
            const float val = m + logf(s);
            table[(((size_t)l * LL + i) * LL + j) * BB + b]  = val;
            tableB[(((size_t)l * LL + j) * LL + i) * BB + b] = val;
        }
        return;
    }

    if (t < E0 + E1) {
        // ---------------- d1: gap G+1
        const int o = t - E0;
        const int r = o & 15;
        const int cell = o >> 4;
        const int b = cell & 7;
        int i, l; tri_decode(cell >> 3, i, l);
        const int j = i + G + 1;

        const float* Tli  = table  + ((size_t)(l * LL + i) * LL) * BB + b;
        const float* TijB = tableB + ((size_t)(i * LL + j) * LL) * BB + b;
        const float* rlT  = red_logT + ((size_t)j * LL) * BB + b;

        float m = -3.4e38f, s = 0.f;
        if (r < 4) {
            const float* Tij1B = tableB + ((size_t)(i * LL + (j - 1)) * LL) * BB + b;
            const float* rl1T  = red_logT + ((size_t)(j - 1) * LL) * BB + b;
#pragma unroll
            for (int d = 0; d < (G + 2) / 4; d++) {
                const int k = i + 1 + r + 4 * d;
                const float x = (k < j - 1) ? (Tli[k * 8] + Tij1B[k * 8] + rl1T[k * 8])
                                            : -INFINITY;
                lse_step(m, s, x);
            }
        } else if (r < 8) {
            const float* Ti1k = table  + ((size_t)(i * LL + (i + 1)) * LL) * BB + b;
            const float* TkjB = tableB + ((size_t)((i + 1) * LL + j) * LL) * BB + b;
#pragma unroll
            for (int d = 0; d < (G + 2) / 4; d++) {
                const int k = i + 2 + (r - 4) + 4 * d;
                const float x = (k < j) ? (Ti1k[k * 8] + TkjB[k * 8] + rlT[k * 8])
                                        : -INFINITY;
                lse_step(m, s, x);
            }
        } else {
#pragma unroll
            for (int d = 0; d < (G + 5) / 8; d++) {
                const int k = i + 2 + (r - 8) + 8 * d;
                const float x = (k < j - 1) ? (Tli[k * 8] + TijB[k * 8] + rlT[k * 8])
                                            : -INFINITY;
                lse_step(m, s, x);
            }
        }
        lse_comb(m, s, __shfl_xor(m, 1, 64), __shfl_xor(s, 1, 64));
        lse_comb(m, s, __shfl_xor(m, 2, 64), __shfl_xor(s, 2, 64));
        if (r >= 8)
            lse_comb(m, s, __shfl_xor(m, 4, 64), __shfl_xor(s, 4, 64));
        const int base = (threadIdx.x & 63) & ~15;
        float m1 = __shfl(m, base + 0, 64), s1 = __shfl(s, base + 0, 64);
        float m2 = __shfl(m, base + 4, 64), s2 = __shfl(s, base + 4, 64);
        float M  = __shfl(m, base + 8, 64), S  = __shfl(s, base + 8, 64);
        const float r1 = m1 + logf(s1);
        const float r2 = m2 + logf(s2);
        lse_step(M, S, Tli[(i + 1) * 8] + r2 + rlT[(i + 1) * 8]);
        lse_step(M, S, r1 + TijB[(j - 1) * 8] + rlT[(j - 1) * 8]);
        const float val = M + logf(S);
        if (r == 0) {
            table[(((size_t)l * LL + i) * LL + j) * BB + b]  = val;
            tableB[(((size_t)l * LL + j) * LL + i) * BB + b] = val;
            if (i == 0 && l == 0 && j == NSENT) out[b] = val;
        }
        return;
    }

    // ---------------- d2: gap G+2
    const int o2 = t - E0 - E1;
    if (o2 >= NE2 * 256) return;
    const int r = o2 & 31;
    const int cell = o2 >> 5;
    const int b = cell & 7;
    int i, l; tri_decode(cell >> 3, i, l);
    const int j = i + G + 2;

    const float* Tli  = table  + ((size_t)(l * LL + i) * LL) * BB + b;
    const float* Ti1  = table  + ((size_t)(i * LL + (i + 1)) * LL) * BB + b;
    const float* Ti2  = table  + ((size_t)(i * LL + (i + 2)) * LL) * BB + b;
    const float* Ti12 = table  + ((size_t)((i + 1) * LL + (i + 2)) * LL) * BB + b;
    const float* TBiG  = tableB + ((size_t)(i * LL + (i + G)) * LL) * BB + b;
    const float* TB1G1 = tableB + ((size_t)((i + 1) * LL + (i + G + 1)) * LL) * BB + b;
    const float* TB2j  = tableB + ((size_t)((i + 2) * LL + j) * LL) * BB + b;
    const float* TBiG1 = tableB + ((size_t)(i * LL + (i + G + 1)) * LL) * BB + b;
    const float* TB1j  = tableB + ((size_t)((i + 1) * LL + j) * LL) * BB + b;
    const float* TBij  = tableB + ((size_t)(i * LL + j) * LL) * BB + b;
    const float* Rj  = red_logT + ((size_t)j * LL) * BB + b;
    const float* RG  = red_logT + ((size_t)(i + G) * LL) * BB + b;
    const float* RG1 = red_logT + ((size_t)(i + G + 1) * LL) * BB + b;

    const int loop = r >> 2, s4 = r & 3;
    const float *A, *Bp, *R;
    int ks, ke;
    switch (loop) {
        case 0: A = Tli;  Bp = TBiG;  R = RG;  ks = i + 1; ke = i + G;     break; // P1
        case 1: A = Ti1;  Bp = TB1G1; R = RG1; ks = i + 2; ke = i + G + 1; break; // P3
        case 2: A = Ti2;  Bp = TB2j;  R = Rj;  ks = i + 3; ke = i + G + 2; break; // P4
        case 3: A = Ti12; Bp = TB2j;  R = Rj;  ks = i + 3; ke = i + G + 2; break; // P6
        case 4: A = Tli;  Bp = TBiG1; R = RG1; ks = i + 2; ke = i + G;     break; // P2mid
        case 5: A = Ti1;  Bp = TB1j;  R = Rj;  ks = i + 3; ke = i + G + 1; break; // P5mid
        case 6: A = Tli;  Bp = TBij;  R = Rj;  ks = i + 3; ke = i + G;     break; // mainmid
        default: A = Tli; Bp = TBij;  R = Rj;  ks = 0;     ke = 0;         break; // idle
    }
    float m = -3.4e38f, s = 0.f;
#pragma unroll
    for (int d = 0; d < (G + 2) / 4; d++) {
        const int k = ks + s4 + 4 * d;
        const float x = (k < ke) ? (A[k * 8] + Bp[k * 8] + R[k * 8]) : -INFINITY;
        lse_step(m, s, x);
    }
    lse_comb(m, s, __shfl_xor(m, 1, 64), __shfl_xor(s, 1, 64));
    lse_comb(m, s, __shfl_xor(m, 2, 64), __shfl_xor(s, 2, 64));
    const int wb = (threadIdx.x & 63) & ~31;
    float mv[7], sv[7];
#pragma unroll
    for (int q = 0; q < 7; q++) {
        mv[q] = __shfl(m, wb + 4 * q, 64);
        sv[q] = __shfl(s, wb + 4 * q, 64);
    }
    const float P1v = mv[0] + logf(sv[0]);
    const float P3v = mv[1] + logf(sv[1]);
    const float P4v = mv[2] + logf(sv[2]);
    const float P6v = mv[3] + logf(sv[3]);
    float m2 = mv[4], s2 = sv[4];
    lse_step(m2, s2, Tli[(i + 1) * 8] + P3v + RG1[(i + 1) * 8]);
    lse_step(m2, s2, P1v + table[(((size_t)i * LL + (i + G)) * LL + (i + G + 1)) * BB + b]
                     + RG1[(i + G) * 8]);
    const float P2v = m2 + logf(s2);
    float m5 = mv[5], s5 = sv[5];
    lse_step(m5, s5, Ti1[(i + 2) * 8] + P6v + Rj[(i + 2) * 8]);
    lse_step(m5, s5, P3v + table[(((size_t)(i + 1) * LL + (i + G + 1)) * LL + j) * BB + b]
                     + Rj[(i + G + 1) * 8]);
    const float P5v = m5 + logf(s5);
    float M = mv[6], S = sv[6];
    lse_step(M, S, Tli[(i + 1) * 8] + P5v + Rj[(i + 1) * 8]);
    lse_step(M, S, P2v + table[(((size_t)i * LL + (i + G + 1)) * LL + j) * BB + b]
                   + Rj[(i + G + 1) * 8]);
    if (G > 2) {
        lse_step(M, S, Tli[(i + 2) * 8] + P4v + Rj[(i + 2) * 8]);
        lse_step(M, S, P1v + table[(((size_t)i * LL + (i + G)) * LL + j) * BB + b]
                       + Rj[(i + G) * 8]);
    } else {
        lse_step(M, S, P1v + P4v + Rj[(i + 2) * 8]);   // k=i+2 == i+G
    }
    const float val = M + logf(S);
    if (r == 0) {
        table[(((size_t)l * LL + i) * LL + j) * BB + b]  = val;
        tableB[(((size_t)l * LL + j) * LL + i) * BB + b] = val;
    }
}

static void launch_dp(int G, const float* red_logT, float* table, float* tableB,
                      float* out, hipStream_t stream) {
    const int NE0 = (64 - G) * (65 - G) / 2;
    const int NE1 = (63 - G) * (64 - G) / 2;
    const int NE2 = (62 - G) * (63 - G) / 2;
    const int total = NE0 * 32 + NE1 * 128 + NE2 * 256;
    const int blocks = (total + 255) / 256;
#define DPC(GG) case GG: dp_triple_t<GG><<<blocks, 256, 0, stream>>>(red_logT, table, tableB, out); break;
    switch (G) {
        DPC(2)  DPC(5)  DPC(8)  DPC(11) DPC(14) DPC(17) DPC(20)
        DPC(23) DPC(26) DPC(29) DPC(32) DPC(35) DPC(38) DPC(41)
        DPC(44) DPC(47) DPC(50) DPC(53) DPC(56) DPC(59) DPC(62)
    }
#undef DPC
}

// ---------------------------------------------------------------- launch
extern "C" void kernel_launch(void* const* d_in, const int* in_sizes, int n_in,
                              void* d_out, int out_size, void* d_ws, size_t ws_size,
                              hipStream_t stream) {
    const float* enc      = (const float*)d_in[0];
    const int*   sentence = (const int*)  d_in[1];
    const float* W1t      = (const float*)d_in[2];
    const float* b1t      = (const float*)d_in[3];
    const float* W2t      = (const float*)d_in[4];
    const float* b2t      = (const float*)d_in[5];
    const float* W1w      = (const float*)d_in[6];
    const float* b1w      = (const float*)d_in[7];
    const float* W2w      = (const float*)d_in[8];
    const float* b2w      = (const float*)d_in[9];
    float* out = (float*)d_out;

    float* base = (float*)d_ws;
    float* table    = base;                base += (size_t)LL * LL * LL * BB;   // 8 MB
    float* tableB   = base;                base += (size_t)LL * LL * LL * BB;   // 8 MB
    float* sh_log   = base;                base += LL * LL * BB;
    float* red_log  = base;                base += LL * LL * BB;
    float* red_logT = base;                base += LL * LL * BB;
    float* UL       = base;                base += 4 * 512 * 512;
    float* part_s   = base;                base += (size_t)128 * MPAD;
    float* gval     = base;                base += MPAD;
    int*   words    = (int*)base;          base += MPAD;
    int*   pair_i   = (int*)base;          base += 2048;
    int*   pair_j   = (int*)base;          base += 2048;
    uchar* h8       = (uchar*)base;        base += (size_t)MPAD * HH / 4;
    uchar* w2w8     = (uchar*)base;        base += (size_t)VV * HH / 4;

    ulw2wt_kernel<<<1288, 256, 0, stream>>>(enc, W1t, W1w, W2w, sentence,
                                            UL, w2w8, pair_i, pair_j, words);
    pairs_kernel<<<NPITEM, 256, 0, stream>>>(UL, b1t, W2t, b2t, b1w,
                                             pair_i, pair_j, words, w2w8, b2w,
                                             sh_log, red_log, red_logT, h8, gval);
    gemm_kernel<<<127 * 64, 256, 0, stream>>>(h8, w2w8, b2w, part_s);
    combine_kernel<<<64, 256, 0, stream>>>(part_s, gval, sh_log, pair_i, pair_j,
                                           table, tableB);
    for (int G = 2; G <= 62; G += 3)
        launch_dp(G, red_logT, table, tableB, out, stream);
}